// Round 1
// baseline (634.796 us; speedup 1.0000x reference)
//
#include <hip/hip_runtime.h>
#include <math.h>

// Problem constants (from reference setup_inputs)
#define N_B 4
#define N_H 16
#define L_Q 2048
#define L_K 2048
#define E_D 1024
#define DH  64
#define QB  64
#define KB  64
#define LDP 72          // padded LDS row stride (elements) to break bank conflicts
#define NT  256
#define NQT (L_Q / QB)  // 32 q-tiles
#define NKT (L_K / KB)  // 32 k-tiles

typedef _Float16 f16x8 __attribute__((ext_vector_type(8)));
typedef float    f32x4 __attribute__((ext_vector_type(4)));

__global__ __launch_bounds__(NT)
void mha_fwd_kernel(const float* __restrict__ Qg, const float* __restrict__ Kg,
                    const float* __restrict__ Vg, const int* __restrict__ causp,
                    float* __restrict__ Yg, float* __restrict__ Wg)
{
    __shared__ __attribute__((aligned(16))) _Float16 Qs[QB][LDP];
    __shared__ __attribute__((aligned(16))) _Float16 Ks[KB][LDP];
    __shared__ __attribute__((aligned(16))) _Float16 Vt[DH][LDP];  // Vt[d][kk]
    __shared__ __attribute__((aligned(16))) _Float16 Ps[QB][LDP];

    const int tid  = threadIdx.x;
    const int lane = tid & 63;
    const int wid  = tid >> 6;          // wave id 0..3, band of 16 q-rows
    const int bid  = blockIdx.x;
    const int qt   = bid & (NQT - 1);
    const int nh   = bid >> 5;          // n*16 + h
    const int q0   = qt * QB;
    const int n    = nh >> 4;
    const int h    = nh & 15;
    const bool causal = (*causp) != 0;
    const float scale = 0.125f;         // 1/sqrt(64)

    const float* Qbase = Qg + ((size_t)(n * L_Q + q0)) * E_D + h * DH;
    const float* Kbase = Kg + ((size_t)n * L_K) * E_D + h * DH;
    const float* Vbase = Vg + ((size_t)n * L_K) * E_D + h * DH;
    float*       Ybase = Yg + ((size_t)(n * L_Q + q0)) * E_D + h * DH;
    float*       Wbase = Wg + ((size_t)nh * L_Q + q0) * L_K;

    // ---- stage Q tile (fp32 -> fp16), 64x64 ----
    #pragma unroll
    for (int i = 0; i < 4; ++i) {
        int lin = tid + i * NT;
        int r = lin >> 4;
        int c = (lin & 15) * 4;
        float4 qv = *(const float4*)(Qbase + (size_t)r * E_D + c);
        Qs[r][c + 0] = (_Float16)qv.x; Qs[r][c + 1] = (_Float16)qv.y;
        Qs[r][c + 2] = (_Float16)qv.z; Qs[r][c + 3] = (_Float16)qv.w;
    }

    const int lrow = lane & 15;          // col (C/D) / row (A,B frag) within 16
    const int lk   = (lane >> 4) * 8;    // k-offset within 32-wide chunk
    const int rb   = wid * 16;           // band base row
    const int rsub = (lane >> 4) * 4;    // C/D row base within 16x16 tile

    const int kt_end = causal ? (qt + 1) : NKT;

    float m_i[4], l_i[4];
    #pragma unroll
    for (int i = 0; i < 4; ++i) { m_i[i] = -INFINITY; l_i[i] = 0.0f; }

    // ================= PASS A: softmax stats (m, l) =================
    for (int kt = 0; kt < kt_end; ++kt) {
        const float* Kt = Kbase + (size_t)kt * KB * E_D;
        __syncthreads();   // protect Ks readers of previous iteration (and Qs staging)
        #pragma unroll
        for (int i = 0; i < 4; ++i) {
            int lin = tid + i * NT;
            int r = lin >> 4;
            int c = (lin & 15) * 4;
            float4 kv = *(const float4*)(Kt + (size_t)r * E_D + c);
            Ks[r][c + 0] = (_Float16)kv.x; Ks[r][c + 1] = (_Float16)kv.y;
            Ks[r][c + 2] = (_Float16)kv.z; Ks[r][c + 3] = (_Float16)kv.w;
        }
        __syncthreads();

        f32x4 acc[4] = {};
        f16x8 a0 = *(const f16x8*)&Qs[rb + lrow][lk];
        f16x8 a1 = *(const f16x8*)&Qs[rb + lrow][32 + lk];
        #pragma unroll
        for (int tc = 0; tc < 4; ++tc) {
            f16x8 b0 = *(const f16x8*)&Ks[tc * 16 + lrow][lk];
            f16x8 b1 = *(const f16x8*)&Ks[tc * 16 + lrow][32 + lk];
            acc[tc] = __builtin_amdgcn_mfma_f32_16x16x32_f16(a0, b0, acc[tc], 0, 0, 0);
            acc[tc] = __builtin_amdgcn_mfma_f32_16x16x32_f16(a1, b1, acc[tc], 0, 0, 0);
        }

        const bool dm = causal && (kt == qt);
        float s[4][4];
        #pragma unroll
        for (int tc = 0; tc < 4; ++tc) {
            #pragma unroll
            for (int i = 0; i < 4; ++i) {
                float v = acc[tc][i] * scale;
                if (dm) {
                    int kcol = tc * 16 + lrow;   // in-tile col
                    int qrow = rb + rsub + i;    // in-tile row (same tile idx)
                    if (kcol > qrow) v = -INFINITY;
                }
                s[tc][i] = v;
            }
        }
        #pragma unroll
        for (int i = 0; i < 4; ++i) {
            float tm = fmaxf(fmaxf(s[0][i], s[1][i]), fmaxf(s[2][i], s[3][i]));
            tm = fmaxf(tm, __shfl_xor(tm, 1));
            tm = fmaxf(tm, __shfl_xor(tm, 2));
            tm = fmaxf(tm, __shfl_xor(tm, 4));
            tm = fmaxf(tm, __shfl_xor(tm, 8));
            float nm = fmaxf(m_i[i], tm);
            float ss = __expf(s[0][i] - nm) + __expf(s[1][i] - nm)
                     + __expf(s[2][i] - nm) + __expf(s[3][i] - nm);
            ss += __shfl_xor(ss, 1);
            ss += __shfl_xor(ss, 2);
            ss += __shfl_xor(ss, 4);
            ss += __shfl_xor(ss, 8);
            l_i[i] = l_i[i] * __expf(m_i[i] - nm) + ss;
            m_i[i] = nm;
        }
    }

    float inv_l[4];
    #pragma unroll
    for (int i = 0; i < 4; ++i) inv_l[i] = 1.0f / l_i[i];

    // ================= PASS B: P write + O = P*V =================
    f32x4 o[4] = {};
    for (int kt = 0; kt < kt_end; ++kt) {
        const float* Kt  = Kbase + (size_t)kt * KB * E_D;
        const float* Vtg = Vbase + (size_t)kt * KB * E_D;
        __syncthreads();   // protect Ks/Vt/Ps readers of previous iteration
        #pragma unroll
        for (int i = 0; i < 4; ++i) {
            int lin = tid + i * NT;
            int r = lin >> 4;
            int c = (lin & 15) * 4;
            float4 kv = *(const float4*)(Kt + (size_t)r * E_D + c);
            Ks[r][c + 0] = (_Float16)kv.x; Ks[r][c + 1] = (_Float16)kv.y;
            Ks[r][c + 2] = (_Float16)kv.z; Ks[r][c + 3] = (_Float16)kv.w;
            float4 vv = *(const float4*)(Vtg + (size_t)r * E_D + c);
            Vt[c + 0][r] = (_Float16)vv.x; Vt[c + 1][r] = (_Float16)vv.y;
            Vt[c + 2][r] = (_Float16)vv.z; Vt[c + 3][r] = (_Float16)vv.w;
        }
        __syncthreads();

        f32x4 acc[4] = {};
        f16x8 a0 = *(const f16x8*)&Qs[rb + lrow][lk];
        f16x8 a1 = *(const f16x8*)&Qs[rb + lrow][32 + lk];
        #pragma unroll
        for (int tc = 0; tc < 4; ++tc) {
            f16x8 b0 = *(const f16x8*)&Ks[tc * 16 + lrow][lk];
            f16x8 b1 = *(const f16x8*)&Ks[tc * 16 + lrow][32 + lk];
            acc[tc] = __builtin_amdgcn_mfma_f32_16x16x32_f16(a0, b0, acc[tc], 0, 0, 0);
            acc[tc] = __builtin_amdgcn_mfma_f32_16x16x32_f16(a1, b1, acc[tc], 0, 0, 0);
        }

        const bool dm = causal && (kt == qt);
        float* Wt = Wbase + kt * KB;
        #pragma unroll
        for (int tc = 0; tc < 4; ++tc) {
            #pragma unroll
            for (int i = 0; i < 4; ++i) {
                float v = acc[tc][i] * scale;
                if (dm) {
                    int kcol = tc * 16 + lrow;
                    int qrow = rb + rsub + i;
                    if (kcol > qrow) v = -INFINITY;
                }
                float p = __expf(v - m_i[i]) * inv_l[i];
                Ps[rb + rsub + i][tc * 16 + lrow] = (_Float16)p;
                Wt[(size_t)(rb + rsub + i) * L_K + tc * 16 + lrow] = p;  // f32 attn out
            }
        }
        __syncthreads();   // Ps complete

        f16x8 p0 = *(const f16x8*)&Ps[rb + lrow][lk];
        f16x8 p1 = *(const f16x8*)&Ps[rb + lrow][32 + lk];
        #pragma unroll
        for (int tc = 0; tc < 4; ++tc) {
            f16x8 v0 = *(const f16x8*)&Vt[tc * 16 + lrow][lk];
            f16x8 v1 = *(const f16x8*)&Vt[tc * 16 + lrow][32 + lk];
            o[tc] = __builtin_amdgcn_mfma_f32_16x16x32_f16(p0, v0, o[tc], 0, 0, 0);
            o[tc] = __builtin_amdgcn_mfma_f32_16x16x32_f16(p1, v1, o[tc], 0, 0, 0);
        }
    }

    // ---- write Y (64 x 64 f32) ----
    #pragma unroll
    for (int tc = 0; tc < 4; ++tc) {
        #pragma unroll
        for (int i = 0; i < 4; ++i) {
            Ybase[(size_t)(rb + rsub + i) * E_D + tc * 16 + lrow] = o[tc][i];
        }
    }

    // ---- zero-fill masked upper columns of attn ----
    if (causal && kt_end < NKT) {
        const int c0 = kt_end * KB;
        const int rem4 = (L_K - c0) >> 2;
        const float4 z = make_float4(0.f, 0.f, 0.f, 0.f);
        for (int r = 0; r < QB; ++r) {
            float* row = Wbase + (size_t)r * L_K + c0;
            for (int c4 = tid; c4 < rem4; c4 += NT) {
                *(float4*)(row + c4 * 4) = z;
            }
        }
    }
}

extern "C" void kernel_launch(void* const* d_in, const int* in_sizes, int n_in,
                              void* d_out, int out_size, void* d_ws, size_t ws_size,
                              hipStream_t stream) {
    const float* Q  = (const float*)d_in[0];
    const float* K  = (const float*)d_in[1];
    const float* V  = (const float*)d_in[2];
    const int* caus = (const int*)d_in[3];
    float* Y = (float*)d_out;
    float* W = (float*)d_out + (size_t)N_B * L_Q * E_D;  // y first, then attn weights

    dim3 grid(N_B * N_H * NQT);   // 2048 workgroups
    dim3 block(NT);
    hipLaunchKernelGGL(mha_fwd_kernel, grid, block, 0, stream, Q, K, V, caus, Y, W);
}

// Round 3
// 609.979 us; speedup vs baseline: 1.0407x; 1.0407x over previous
//
#include <hip/hip_runtime.h>
#include <math.h>

// Problem constants (from reference setup_inputs)
#define N_B 4
#define N_H 16
#define L_Q 2048
#define L_K 2048
#define E_D 1024
#define DH  64
#define QB  64
#define KB  64
#define LDP  72   // padded row stride (f16) for Qs/Ks/Ps: 144B, 16B-aligned rows
#define LDPV 68   // padded row stride (f16) for Vt: 136B, 8B-aligned rows, 2-way banks
#define NT  256
#define NQT (L_Q / QB)  // 32 q-tiles
#define NKT (L_K / KB)  // 32 k-tiles

typedef _Float16 f16x2 __attribute__((ext_vector_type(2)));
typedef _Float16 f16x4 __attribute__((ext_vector_type(4)));
typedef _Float16 f16x8 __attribute__((ext_vector_type(8)));
typedef float    f32x4 __attribute__((ext_vector_type(4)));

__device__ __forceinline__ f16x4 pk4(float a, float b, float c, float d) {
    f16x2 lo = __builtin_bit_cast(f16x2, __builtin_amdgcn_cvt_pkrtz(a, b));
    f16x2 hi = __builtin_bit_cast(f16x2, __builtin_amdgcn_cvt_pkrtz(c, d));
    f16x4 r; r[0] = lo[0]; r[1] = lo[1]; r[2] = hi[0]; r[3] = hi[1];
    return r;
}

__global__ __launch_bounds__(NT)
void mha_fwd_kernel(const float* __restrict__ Qg, const float* __restrict__ Kg,
                    const float* __restrict__ Vg, const int* __restrict__ causp,
                    float* __restrict__ Yg, float* __restrict__ Wg)
{
    __shared__ __attribute__((aligned(16))) _Float16 Qs[QB][LDP];
    __shared__ __attribute__((aligned(16))) _Float16 Ks[KB][LDP];
    __shared__ __attribute__((aligned(16))) _Float16 Ps[QB][LDP];
    __shared__ __attribute__((aligned(16))) _Float16 Vt[DH][LDPV];  // Vt[d][kk]

    const int tid  = threadIdx.x;
    const int lane = tid & 63;
    const int wid  = tid >> 6;          // wave id 0..3, band of 16 q-rows
    const int bid  = blockIdx.x;
    const int qt   = bid & (NQT - 1);
    const int nh   = bid >> 5;          // n*16 + h
    const int q0   = qt * QB;
    const int n    = nh >> 4;
    const int h    = nh & 15;
    const bool causal = (*causp) != 0;
    const float scale = 0.125f;         // 1/sqrt(64)

    const float* Qbase = Qg + ((size_t)(n * L_Q + q0)) * E_D + h * DH;
    const float* Kbase = Kg + ((size_t)n * L_K) * E_D + h * DH;
    const float* Vbase = Vg + ((size_t)n * L_K) * E_D + h * DH;
    float*       Ybase = Yg + ((size_t)(n * L_Q + q0)) * E_D + h * DH;
    float*       Wbase = Wg + ((size_t)nh * L_Q + q0) * L_K;

    const int lrow = lane & 15;          // q (C/D col; B-frag col); K/V row in frags
    const int lk   = (lane >> 4) * 8;    // k-offset within 32-wide chunk
    const int rb   = wid * 16;           // this wave's q-band base row
    const int rsub = (lane >> 4) * 4;    // C/D row base within 16x16 tile

    const int kt_end = causal ? (qt + 1) : NKT;

    // ---- stage Q tile (fp32 -> fp16, packed) ----
    #pragma unroll
    for (int i = 0; i < 4; ++i) {
        int lin = tid + i * NT;
        int r = lin >> 4;
        int c = (lin & 15) * 4;
        float4 qv = *(const float4*)(Qbase + (size_t)r * E_D + c);
        *(f16x4*)&Qs[r][c] = pk4(qv.x, qv.y, qv.z, qv.w);
    }
    __syncthreads();
    // Q is the MFMA B-operand now (j = q = lane&15); loop-invariant -> hoist.
    const f16x8 qf0 = *(const f16x8*)&Qs[rb + lrow][lk];
    const f16x8 qf1 = *(const f16x8*)&Qs[rb + lrow][32 + lk];

    // ================= PASS A: row sums (m == 0 fixed) =================
    float l_part = 0.0f;
    for (int kt = 0; kt < kt_end; ++kt) {
        const float* Kt = Kbase + (size_t)kt * KB * E_D;
        __syncthreads();   // protect previous Ks readers
        #pragma unroll
        for (int i = 0; i < 4; ++i) {
            int lin = tid + i * NT;
            int r = lin >> 4;
            int c = (lin & 15) * 4;
            float4 kv = *(const float4*)(Kt + (size_t)r * E_D + c);
            *(f16x4*)&Ks[r][c] = pk4(kv.x, kv.y, kv.z, kv.w);
        }
        __syncthreads();

        f32x4 acc[4] = {};
        #pragma unroll
        for (int tc = 0; tc < 4; ++tc) {
            f16x8 a0 = *(const f16x8*)&Ks[tc * 16 + lrow][lk];
            f16x8 a1 = *(const f16x8*)&Ks[tc * 16 + lrow][32 + lk];
            acc[tc] = __builtin_amdgcn_mfma_f32_16x16x32_f16(a0, qf0, acc[tc], 0, 0, 0);
            acc[tc] = __builtin_amdgcn_mfma_f32_16x16x32_f16(a1, qf1, acc[tc], 0, 0, 0);
        }

        const bool dm = causal && (kt == qt);
        #pragma unroll
        for (int tc = 0; tc < 4; ++tc) {
            #pragma unroll
            for (int i = 0; i < 4; ++i) {
                float v = acc[tc][i] * scale;       // S[q=rb+lrow][kcol=tc*16+rsub+i]
                bool ok = !dm || (tc * 16 + rsub + i <= rb + lrow);
                l_part += ok ? __expf(v) : 0.0f;
            }
        }
    }
    // one reduce at the very end: lanes {q, q+16, q+32, q+48} share a row
    l_part += __shfl_xor(l_part, 16);
    l_part += __shfl_xor(l_part, 32);
    const float inv_l = 1.0f / l_part;

    // ================= PASS B: P write + O^T = V^T * P^T =================
    f32x4 o[4] = {};
    for (int kt = 0; kt < kt_end; ++kt) {
        const float* Kt  = Kbase + (size_t)kt * KB * E_D;
        const float* Vtg = Vbase + (size_t)kt * KB * E_D;
        __syncthreads();   // protect previous Ks/Vt readers
        #pragma unroll
        for (int i = 0; i < 4; ++i) {
            int lin = tid + i * NT;
            int r = lin >> 4;
            int c = (lin & 15) * 4;
            float4 kv = *(const float4*)(Kt + (size_t)r * E_D + c);
            *(f16x4*)&Ks[r][c] = pk4(kv.x, kv.y, kv.z, kv.w);
            // V staged transposed: column-order coalesced loads, packed b64 write
            int cidx = tid + i * NT;
            int d    = cidx & 63;
            int kk0  = (cidx >> 6) * 4;
            float v0 = Vtg[(size_t)(kk0 + 0) * E_D + d];
            float v1 = Vtg[(size_t)(kk0 + 1) * E_D + d];
            float v2 = Vtg[(size_t)(kk0 + 2) * E_D + d];
            float v3 = Vtg[(size_t)(kk0 + 3) * E_D + d];
            *(f16x4*)&Vt[d][kk0] = pk4(v0, v1, v2, v3);
        }
        __syncthreads();

        f32x4 acc[4] = {};
        #pragma unroll
        for (int tc = 0; tc < 4; ++tc) {
            f16x8 a0 = *(const f16x8*)&Ks[tc * 16 + lrow][lk];
            f16x8 a1 = *(const f16x8*)&Ks[tc * 16 + lrow][32 + lk];
            acc[tc] = __builtin_amdgcn_mfma_f32_16x16x32_f16(a0, qf0, acc[tc], 0, 0, 0);
            acc[tc] = __builtin_amdgcn_mfma_f32_16x16x32_f16(a1, qf1, acc[tc], 0, 0, 0);
        }

        const bool dm = causal && (kt == qt);
        float* Wrow = Wbase + (size_t)(rb + lrow) * L_K + kt * KB;
        #pragma unroll
        for (int tc = 0; tc < 4; ++tc) {
            float p0, p1, p2, p3;
            {
                float v;
                v = acc[tc][0] * scale;
                p0 = (!dm || (tc * 16 + rsub + 0 <= rb + lrow)) ? __expf(v) : 0.0f;
                v = acc[tc][1] * scale;
                p1 = (!dm || (tc * 16 + rsub + 1 <= rb + lrow)) ? __expf(v) : 0.0f;
                v = acc[tc][2] * scale;
                p2 = (!dm || (tc * 16 + rsub + 2 <= rb + lrow)) ? __expf(v) : 0.0f;
                v = acc[tc][3] * scale;
                p3 = (!dm || (tc * 16 + rsub + 3 <= rb + lrow)) ? __expf(v) : 0.0f;
            }
            float4 wv = make_float4(p0 * inv_l, p1 * inv_l, p2 * inv_l, p3 * inv_l);
            *(float4*)(Wrow + tc * 16 + rsub) = wv;               // normalized f32 attn
            *(f16x4*)&Ps[rb + lrow][tc * 16 + rsub] = pk4(p0, p1, p2, p3);  // unnorm f16
        }
        // Ps rows rb..rb+15 are written and read only by this wave: no barrier,
        // the compiler's lgkmcnt handles the write->read ordering.

        f16x8 pf0 = *(const f16x8*)&Ps[rb + lrow][lk];
        f16x8 pf1 = *(const f16x8*)&Ps[rb + lrow][32 + lk];
        #pragma unroll
        for (int tc = 0; tc < 4; ++tc) {
            f16x4 t0 = *(const f16x4*)&Vt[tc * 16 + lrow][lk];
            f16x4 t1 = *(const f16x4*)&Vt[tc * 16 + lrow][lk + 4];
            f16x8 a0 = __builtin_shufflevector(t0, t1, 0, 1, 2, 3, 4, 5, 6, 7);
            f16x4 t2 = *(const f16x4*)&Vt[tc * 16 + lrow][32 + lk];
            f16x4 t3 = *(const f16x4*)&Vt[tc * 16 + lrow][32 + lk + 4];
            f16x8 a1 = __builtin_shufflevector(t2, t3, 0, 1, 2, 3, 4, 5, 6, 7);
            o[tc] = __builtin_amdgcn_mfma_f32_16x16x32_f16(a0, pf0, o[tc], 0, 0, 0);
            o[tc] = __builtin_amdgcn_mfma_f32_16x16x32_f16(a1, pf1, o[tc], 0, 0, 0);
        }
    }

    // ---- write Y: lane owns row q=rb+lrow; o[tc][i] = O^T[d=tc*16+rsub+i][q] ----
    #pragma unroll
    for (int tc = 0; tc < 4; ++tc) {
        float4 yv = make_float4(o[tc][0] * inv_l, o[tc][1] * inv_l,
                                o[tc][2] * inv_l, o[tc][3] * inv_l);
        *(float4*)(Ybase + (size_t)(rb + lrow) * E_D + tc * 16 + rsub) = yv;
    }

    // ---- zero-fill masked upper columns of attn ----
    if (causal && kt_end < NKT) {
        const int c0 = kt_end * KB;
        const int rem4 = (L_K - c0) >> 2;
        const float4 z = make_float4(0.f, 0.f, 0.f, 0.f);
        for (int r = 0; r < QB; ++r) {
            float* row = Wbase + (size_t)r * L_K + c0;
            for (int c4 = tid; c4 < rem4; c4 += NT) {
                *(float4*)(row + c4 * 4) = z;
            }
        }
    }
}

extern "C" void kernel_launch(void* const* d_in, const int* in_sizes, int n_in,
                              void* d_out, int out_size, void* d_ws, size_t ws_size,
                              hipStream_t stream) {
    const float* Q  = (const float*)d_in[0];
    const float* K  = (const float*)d_in[1];
    const float* V  = (const float*)d_in[2];
    const int* caus = (const int*)d_in[3];
    float* Y = (float*)d_out;
    float* W = (float*)d_out + (size_t)N_B * L_Q * E_D;  // y first, then attn weights

    dim3 grid(N_B * N_H * NQT);   // 2048 workgroups
    dim3 block(NT);
    hipLaunchKernelGGL(mha_fwd_kernel, grid, block, 0, stream, Q, K, V, caus, Y, W);
}

// Round 4
// 360.919 us; speedup vs baseline: 1.7588x; 1.6901x over previous
//
#include <hip/hip_runtime.h>
#include <math.h>
#include <stdint.h>

// Problem constants
#define N_B 4
#define N_H 16
#define L_Q 2048
#define L_K 2048
#define E_D 1024
#define DH  64
#define QB  64
#define KB  64
#define NT  256
#define NQT (L_Q / QB)  // 32
#define NKT (L_K / KB)  // 32
#define LDP  72   // padded stride for Ps (f16)
#define LDPV 68

typedef _Float16 f16x2 __attribute__((ext_vector_type(2)));
typedef _Float16 f16x4 __attribute__((ext_vector_type(4)));
typedef _Float16 f16x8 __attribute__((ext_vector_type(8)));
typedef float    f32x4 __attribute__((ext_vector_type(4)));

__device__ __forceinline__ f16x4 pk4(float a, float b, float c, float d) {
    f16x2 lo = __builtin_bit_cast(f16x2, __builtin_amdgcn_cvt_pkrtz(a, b));
    f16x2 hi = __builtin_bit_cast(f16x2, __builtin_amdgcn_cvt_pkrtz(c, d));
    f16x4 r; r[0] = lo[0]; r[1] = lo[1]; r[2] = hi[0]; r[3] = hi[1];
    return r;
}

__device__ __forceinline__ void gload16(const _Float16* g, _Float16* l) {
    __builtin_amdgcn_global_load_lds(
        (const __attribute__((address_space(1))) void*)g,
        (__attribute__((address_space(3))) void*)l, 16, 0, 0);
}

// ======================= prep kernels =======================
__global__ __launch_bounds__(NT)
void cvt_qk(const float* __restrict__ Q, const float* __restrict__ K,
            _Float16* __restrict__ Qh, _Float16* __restrict__ Kh)
{
    size_t i = ((size_t)blockIdx.x * NT + threadIdx.x) * 8;
    float4 a = *(const float4*)(Q + i);
    float4 b = *(const float4*)(Q + i + 4);
    *(f16x4*)(Qh + i)     = pk4(a.x, a.y, a.z, a.w);
    *(f16x4*)(Qh + i + 4) = pk4(b.x, b.y, b.z, b.w);
    float4 c = *(const float4*)(K + i);
    float4 d = *(const float4*)(K + i + 4);
    *(f16x4*)(Kh + i)     = pk4(c.x, c.y, c.z, c.w);
    *(f16x4*)(Kh + i + 4) = pk4(d.x, d.y, d.z, d.w);
}

__global__ __launch_bounds__(NT)
void cvt_vt(const float* __restrict__ V, _Float16* __restrict__ Vt)
{
    __shared__ _Float16 T[64][72];
    const int bid = blockIdx.x;
    const int st  = bid & 31;        // s-tile
    const int nh  = bid >> 5;
    const int n   = nh >> 4;
    const int h   = nh & 15;
    const int t   = threadIdx.x;
    const float* Vb = V + ((size_t)(n * L_K + st * 64)) * E_D + h * DH;
    #pragma unroll
    for (int i = 0; i < 4; ++i) {
        int lin = t + i * NT;            // 1024 float4 slots
        int s = lin >> 4, d = (lin & 15) * 4;
        float4 v = *(const float4*)(Vb + (size_t)s * E_D + d);
        T[d + 0][s] = (_Float16)v.x; T[d + 1][s] = (_Float16)v.y;
        T[d + 2][s] = (_Float16)v.z; T[d + 3][s] = (_Float16)v.w;
    }
    __syncthreads();
    _Float16* Ob = Vt + ((size_t)nh * DH) * L_K + st * 64;
    #pragma unroll
    for (int j = 0; j < 2; ++j) {
        int lin = t + j * NT;            // 512 16B slots
        int d = lin >> 3, sc = (lin & 7) * 8;
        *(f16x8*)(Ob + (size_t)d * L_K + sc) = *(const f16x8*)&T[d][sc];
    }
}

// ======================= main kernel =======================
__global__ __launch_bounds__(NT)
void mha_main(const _Float16* __restrict__ Qh, const _Float16* __restrict__ Kh,
              const _Float16* __restrict__ Vth, const int* __restrict__ causp,
              float* __restrict__ Yg, float* __restrict__ Wg)
{
    // linear (unpadded) swizzled tiles for global_load_lds; double-buffered
    __shared__ __attribute__((aligned(16))) _Float16 KsL[2][KB * DH];  // 8 KB each
    __shared__ __attribute__((aligned(16))) _Float16 VsL[2][DH * KB];  // 8 KB each
    __shared__ __attribute__((aligned(16))) _Float16 Ps[QB][LDP];

    const int tid  = threadIdx.x;
    const int lane = tid & 63;
    const int wid  = tid >> 6;
    const int bid0 = blockIdx.x;
    // bijective XCD swizzle: 2048 % 8 == 0 -> each XCD gets 8 contiguous (n,h)
    const int bid  = ((bid0 & 7) << 8) + (bid0 >> 3);
    const int qt   = bid & (NQT - 1);
    const int nh   = bid >> 5;
    const int q0   = qt * QB;
    const int n    = nh >> 4;
    const int h    = nh & 15;
    const bool causal = (*causp) != 0;
    const float scale = 0.125f;

    const int lrow = lane & 15;          // q within 16 (C/D col, B-frag col)
    const int g    = lane >> 4;
    const int rb   = wid * 16;           // wave's q-band
    const int rsub = g * 4;
    const int kt_end = causal ? (qt + 1) : NKT;

    float*  Ybase = Yg + ((size_t)(n * L_Q + q0)) * E_D + h * DH;
    float*  Wbase = Wg + ((size_t)nh * L_Q + q0) * L_K;

    // ---- staging source addresses (inverse-swizzled per-lane; rule #21) ----
    const int srow = wid * 16 + (lane >> 3);              // +8 for issue j=1
    const int scol = (((lane & 7) ^ (lane >> 3)) << 3);   // element offset
    const _Float16* Ksrc0 = Kh  + ((size_t)(n * L_K) + srow) * E_D + h * DH + scol;
    const _Float16* Vsrc0 = Vth + ((size_t)nh * DH + srow) * L_K + scol;

    // ---- swizzled fragment read offsets ----
    const int swz = (lrow & 7) << 4;                      // bytes
    const int cb0 = ((g * 16) ^ swz) >> 1;                // elements
    const int cb1 = (((64 + g * 16)) ^ swz) >> 1;

    // ---- Q fragments straight from global f16 ----
    const _Float16* Qrow = Qh + ((size_t)(n * L_Q + q0 + rb + lrow)) * E_D + h * DH;
    const f16x8 qf0 = *(const f16x8*)(Qrow + g * 8);
    const f16x8 qf1 = *(const f16x8*)(Qrow + 32 + g * 8);

    #define STAGE_K(b, kt) { const _Float16* s_ = Ksrc0 + (size_t)(kt) * KB * E_D; \
        gload16(s_,            &KsL[b][(wid * 2 + 0) * 512]); \
        gload16(s_ + 8 * E_D,  &KsL[b][(wid * 2 + 1) * 512]); }
    #define STAGE_V(b, kt) { const _Float16* s_ = Vsrc0 + (size_t)(kt) * KB; \
        gload16(s_,            &VsL[b][(wid * 2 + 0) * 512]); \
        gload16(s_ + 8 * L_K,  &VsL[b][(wid * 2 + 1) * 512]); }
    #define FRAG(buf, tc, half) (*(const f16x8*)&(buf)[(size_t)((tc) * 16 + lrow) * 64 + ((half) ? cb1 : cb0)])

    // ================= PASS A: row sums (m == 0) =================
    float l_part = 0.0f;
    STAGE_K(0, 0);
    __syncthreads();
    for (int kt = 0; kt < kt_end; ++kt) {
        const int cur = kt & 1;
        if (kt + 1 < kt_end) STAGE_K(cur ^ 1, kt + 1);

        f32x4 acc[4] = {};
        #pragma unroll
        for (int tc = 0; tc < 4; ++tc) {
            acc[tc] = __builtin_amdgcn_mfma_f32_16x16x32_f16(FRAG(KsL[cur], tc, 0), qf0, acc[tc], 0, 0, 0);
            acc[tc] = __builtin_amdgcn_mfma_f32_16x16x32_f16(FRAG(KsL[cur], tc, 1), qf1, acc[tc], 0, 0, 0);
        }
        const bool dm = causal && (kt == qt);
        #pragma unroll
        for (int tc = 0; tc < 4; ++tc) {
            #pragma unroll
            for (int i = 0; i < 4; ++i) {
                float v = acc[tc][i] * scale;     // S[q=rb+lrow][k=tc*16+rsub+i]
                bool ok = !dm || (tc * 16 + rsub + i <= rb + lrow);
                l_part += ok ? __expf(v) : 0.0f;
            }
        }
        __syncthreads();   // compiler drains vmcnt before barrier: buf cur^1 ready
    }
    l_part += __shfl_xor(l_part, 16);
    l_part += __shfl_xor(l_part, 32);
    const float inv_l = 1.0f / l_part;

    // ================= PASS B: W write + O^T = V^T P^T =================
    f32x4 o[4] = {};
    STAGE_K(0, 0);
    STAGE_V(0, 0);
    __syncthreads();
    for (int kt = 0; kt < kt_end; ++kt) {
        const int cur = kt & 1;
        if (kt + 1 < kt_end) { STAGE_K(cur ^ 1, kt + 1); STAGE_V(cur ^ 1, kt + 1); }

        f32x4 acc[4] = {};
        #pragma unroll
        for (int tc = 0; tc < 4; ++tc) {
            acc[tc] = __builtin_amdgcn_mfma_f32_16x16x32_f16(FRAG(KsL[cur], tc, 0), qf0, acc[tc], 0, 0, 0);
            acc[tc] = __builtin_amdgcn_mfma_f32_16x16x32_f16(FRAG(KsL[cur], tc, 1), qf1, acc[tc], 0, 0, 0);
        }

        const bool dm = causal && (kt == qt);
        float* Wrow = Wbase + (size_t)(rb + lrow) * L_K + kt * KB;
        #pragma unroll
        for (int tc = 0; tc < 4; ++tc) {
            float p0, p1, p2, p3;
            {
                float v;
                v = acc[tc][0] * scale;
                p0 = (!dm || (tc * 16 + rsub + 0 <= rb + lrow)) ? __expf(v) : 0.0f;
                v = acc[tc][1] * scale;
                p1 = (!dm || (tc * 16 + rsub + 1 <= rb + lrow)) ? __expf(v) : 0.0f;
                v = acc[tc][2] * scale;
                p2 = (!dm || (tc * 16 + rsub + 2 <= rb + lrow)) ? __expf(v) : 0.0f;
                v = acc[tc][3] * scale;
                p3 = (!dm || (tc * 16 + rsub + 3 <= rb + lrow)) ? __expf(v) : 0.0f;
            }
            float4 wv = make_float4(p0 * inv_l, p1 * inv_l, p2 * inv_l, p3 * inv_l);
            *(float4*)(Wrow + tc * 16 + rsub) = wv;
            *(f16x4*)&Ps[rb + lrow][tc * 16 + rsub] = pk4(p0, p1, p2, p3);
        }
        // Ps rows rb..rb+15 written & read by this wave only: no barrier needed.

        f16x8 pf0 = *(const f16x8*)&Ps[rb + lrow][0 + g * 8];
        f16x8 pf1 = *(const f16x8*)&Ps[rb + lrow][32 + g * 8];
        #pragma unroll
        for (int tc = 0; tc < 4; ++tc) {
            o[tc] = __builtin_amdgcn_mfma_f32_16x16x32_f16(FRAG(VsL[cur], tc, 0), pf0, o[tc], 0, 0, 0);
            o[tc] = __builtin_amdgcn_mfma_f32_16x16x32_f16(FRAG(VsL[cur], tc, 1), pf1, o[tc], 0, 0, 0);
        }
        __syncthreads();
    }

    // ---- Y write ----
    #pragma unroll
    for (int tc = 0; tc < 4; ++tc) {
        float4 yv = make_float4(o[tc][0] * inv_l, o[tc][1] * inv_l,
                                o[tc][2] * inv_l, o[tc][3] * inv_l);
        *(float4*)(Ybase + (size_t)(rb + lrow) * E_D + tc * 16 + rsub) = yv;
    }

    // ---- zero-fill masked upper columns ----
    if (causal && kt_end < NKT) {
        const int c0 = kt_end * KB;
        const int rem4 = (L_K - c0) >> 2;
        const float4 z = make_float4(0.f, 0.f, 0.f, 0.f);
        for (int r = 0; r < QB; ++r) {
            float* row = Wbase + (size_t)r * L_K + c0;
            for (int c4 = tid; c4 < rem4; c4 += NT) {
                *(float4*)(row + c4 * 4) = z;
            }
        }
    }
    #undef STAGE_K
    #undef STAGE_V
    #undef FRAG
}

// ======================= fallback (round-3 proven kernel) =======================
__global__ __launch_bounds__(NT)
void mha_fwd_fallback(const float* __restrict__ Qg, const float* __restrict__ Kg,
                      const float* __restrict__ Vg, const int* __restrict__ causp,
                      float* __restrict__ Yg, float* __restrict__ Wg)
{
    __shared__ __attribute__((aligned(16))) _Float16 Qs[QB][LDP];
    __shared__ __attribute__((aligned(16))) _Float16 Ks[KB][LDP];
    __shared__ __attribute__((aligned(16))) _Float16 Psf[QB][LDP];
    __shared__ __attribute__((aligned(16))) _Float16 Vt[DH][LDPV];

    const int tid  = threadIdx.x;
    const int lane = tid & 63;
    const int wid  = tid >> 6;
    const int bid  = blockIdx.x;
    const int qt   = bid & (NQT - 1);
    const int nh   = bid >> 5;
    const int q0   = qt * QB;
    const int n    = nh >> 4;
    const int h    = nh & 15;
    const bool causal = (*causp) != 0;
    const float scale = 0.125f;

    const float* Qbase = Qg + ((size_t)(n * L_Q + q0)) * E_D + h * DH;
    const float* Kbase = Kg + ((size_t)n * L_K) * E_D + h * DH;
    const float* Vbase = Vg + ((size_t)n * L_K) * E_D + h * DH;
    float*       Ybase = Yg + ((size_t)(n * L_Q + q0)) * E_D + h * DH;
    float*       Wbase = Wg + ((size_t)nh * L_Q + q0) * L_K;

    const int lrow = lane & 15;
    const int lk   = (lane >> 4) * 8;
    const int rb   = wid * 16;
    const int rsub = (lane >> 4) * 4;
    const int kt_end = causal ? (qt + 1) : NKT;

    #pragma unroll
    for (int i = 0; i < 4; ++i) {
        int lin = tid + i * NT;
        int r = lin >> 4;
        int c = (lin & 15) * 4;
        float4 qv = *(const float4*)(Qbase + (size_t)r * E_D + c);
        *(f16x4*)&Qs[r][c] = pk4(qv.x, qv.y, qv.z, qv.w);
    }
    __syncthreads();
    const f16x8 qf0 = *(const f16x8*)&Qs[rb + lrow][lk];
    const f16x8 qf1 = *(const f16x8*)&Qs[rb + lrow][32 + lk];

    float l_part = 0.0f;
    for (int kt = 0; kt < kt_end; ++kt) {
        const float* Kt = Kbase + (size_t)kt * KB * E_D;
        __syncthreads();
        #pragma unroll
        for (int i = 0; i < 4; ++i) {
            int lin = tid + i * NT;
            int r = lin >> 4;
            int c = (lin & 15) * 4;
            float4 kv = *(const float4*)(Kt + (size_t)r * E_D + c);
            *(f16x4*)&Ks[r][c] = pk4(kv.x, kv.y, kv.z, kv.w);
        }
        __syncthreads();
        f32x4 acc[4] = {};
        #pragma unroll
        for (int tc = 0; tc < 4; ++tc) {
            f16x8 a0 = *(const f16x8*)&Ks[tc * 16 + lrow][lk];
            f16x8 a1 = *(const f16x8*)&Ks[tc * 16 + lrow][32 + lk];
            acc[tc] = __builtin_amdgcn_mfma_f32_16x16x32_f16(a0, qf0, acc[tc], 0, 0, 0);
            acc[tc] = __builtin_amdgcn_mfma_f32_16x16x32_f16(a1, qf1, acc[tc], 0, 0, 0);
        }
        const bool dm = causal && (kt == qt);
        #pragma unroll
        for (int tc = 0; tc < 4; ++tc) {
            #pragma unroll
            for (int i = 0; i < 4; ++i) {
                float v = acc[tc][i] * scale;
                bool ok = !dm || (tc * 16 + rsub + i <= rb + lrow);
                l_part += ok ? __expf(v) : 0.0f;
            }
        }
    }
    l_part += __shfl_xor(l_part, 16);
    l_part += __shfl_xor(l_part, 32);
    const float inv_l = 1.0f / l_part;

    f32x4 o[4] = {};
    for (int kt = 0; kt < kt_end; ++kt) {
        const float* Kt  = Kbase + (size_t)kt * KB * E_D;
        const float* Vtg = Vbase + (size_t)kt * KB * E_D;
        __syncthreads();
        #pragma unroll
        for (int i = 0; i < 4; ++i) {
            int lin = tid + i * NT;
            int r = lin >> 4;
            int c = (lin & 15) * 4;
            float4 kv = *(const float4*)(Kt + (size_t)r * E_D + c);
            *(f16x4*)&Ks[r][c] = pk4(kv.x, kv.y, kv.z, kv.w);
            int d   = lin & 63;
            int kk0 = (lin >> 6) * 4;
            float v0 = Vtg[(size_t)(kk0 + 0) * E_D + d];
            float v1 = Vtg[(size_t)(kk0 + 1) * E_D + d];
            float v2 = Vtg[(size_t)(kk0 + 2) * E_D + d];
            float v3 = Vtg[(size_t)(kk0 + 3) * E_D + d];
            *(f16x4*)&Vt[d][kk0] = pk4(v0, v1, v2, v3);
        }
        __syncthreads();
        f32x4 acc[4] = {};
        #pragma unroll
        for (int tc = 0; tc < 4; ++tc) {
            f16x8 a0 = *(const f16x8*)&Ks[tc * 16 + lrow][lk];
            f16x8 a1 = *(const f16x8*)&Ks[tc * 16 + lrow][32 + lk];
            acc[tc] = __builtin_amdgcn_mfma_f32_16x16x32_f16(a0, qf0, acc[tc], 0, 0, 0);
            acc[tc] = __builtin_amdgcn_mfma_f32_16x16x32_f16(a1, qf1, acc[tc], 0, 0, 0);
        }
        const bool dm = causal && (kt == qt);
        float* Wrow = Wbase + (size_t)(rb + lrow) * L_K + kt * KB;
        #pragma unroll
        for (int tc = 0; tc < 4; ++tc) {
            float p0, p1, p2, p3;
            {
                float v;
                v = acc[tc][0] * scale;
                p0 = (!dm || (tc * 16 + rsub + 0 <= rb + lrow)) ? __expf(v) : 0.0f;
                v = acc[tc][1] * scale;
                p1 = (!dm || (tc * 16 + rsub + 1 <= rb + lrow)) ? __expf(v) : 0.0f;
                v = acc[tc][2] * scale;
                p2 = (!dm || (tc * 16 + rsub + 2 <= rb + lrow)) ? __expf(v) : 0.0f;
                v = acc[tc][3] * scale;
                p3 = (!dm || (tc * 16 + rsub + 3 <= rb + lrow)) ? __expf(v) : 0.0f;
            }
            float4 wv = make_float4(p0 * inv_l, p1 * inv_l, p2 * inv_l, p3 * inv_l);
            *(float4*)(Wrow + tc * 16 + rsub) = wv;
            *(f16x4*)&Psf[rb + lrow][tc * 16 + rsub] = pk4(p0, p1, p2, p3);
        }
        f16x8 pf0 = *(const f16x8*)&Psf[rb + lrow][lk];
        f16x8 pf1 = *(const f16x8*)&Psf[rb + lrow][32 + lk];
        #pragma unroll
        for (int tc = 0; tc < 4; ++tc) {
            f16x4 t0 = *(const f16x4*)&Vt[tc * 16 + lrow][lk];
            f16x4 t1 = *(const f16x4*)&Vt[tc * 16 + lrow][lk + 4];
            f16x8 a0 = __builtin_shufflevector(t0, t1, 0, 1, 2, 3, 4, 5, 6, 7);
            f16x4 t2 = *(const f16x4*)&Vt[tc * 16 + lrow][32 + lk];
            f16x4 t3 = *(const f16x4*)&Vt[tc * 16 + lrow][32 + lk + 4];
            f16x8 a1 = __builtin_shufflevector(t2, t3, 0, 1, 2, 3, 4, 5, 6, 7);
            o[tc] = __builtin_amdgcn_mfma_f32_16x16x32_f16(a0, pf0, o[tc], 0, 0, 0);
            o[tc] = __builtin_amdgcn_mfma_f32_16x16x32_f16(a1, pf1, o[tc], 0, 0, 0);
        }
    }
    #pragma unroll
    for (int tc = 0; tc < 4; ++tc) {
        float4 yv = make_float4(o[tc][0] * inv_l, o[tc][1] * inv_l,
                                o[tc][2] * inv_l, o[tc][3] * inv_l);
        *(float4*)(Ybase + (size_t)(rb + lrow) * E_D + tc * 16 + rsub) = yv;
    }
    if (causal && kt_end < NKT) {
        const int c0 = kt_end * KB;
        const int rem4 = (L_K - c0) >> 2;
        const float4 z = make_float4(0.f, 0.f, 0.f, 0.f);
        for (int r = 0; r < QB; ++r) {
            float* row = Wbase + (size_t)r * L_K + c0;
            for (int c4 = tid; c4 < rem4; c4 += NT) {
                *(float4*)(row + c4 * 4) = z;
            }
        }
    }
}

extern "C" void kernel_launch(void* const* d_in, const int* in_sizes, int n_in,
                              void* d_out, int out_size, void* d_ws, size_t ws_size,
                              hipStream_t stream) {
    const float* Q  = (const float*)d_in[0];
    const float* K  = (const float*)d_in[1];
    const float* V  = (const float*)d_in[2];
    const int* caus = (const int*)d_in[3];
    float* Y = (float*)d_out;
    float* W = (float*)d_out + (size_t)N_B * L_Q * E_D;

    const size_t elems = (size_t)N_B * L_Q * E_D;        // 8.4M
    const size_t need  = 3 * elems * sizeof(_Float16);   // ~48 MB

    if (ws_size >= need) {
        _Float16* Qh = (_Float16*)d_ws;
        _Float16* Kh = Qh + elems;
        _Float16* Vt = Kh + elems;
        hipLaunchKernelGGL(cvt_qk, dim3(elems / (NT * 8)), dim3(NT), 0, stream, Q, K, Qh, Kh);
        hipLaunchKernelGGL(cvt_vt, dim3(N_B * N_H * (L_K / 64)), dim3(NT), 0, stream, V, Vt);
        hipLaunchKernelGGL(mha_main, dim3(N_B * N_H * NQT), dim3(NT), 0, stream,
                           Qh, Kh, Vt, caus, Y, W);
    } else {
        hipLaunchKernelGGL(mha_fwd_fallback, dim3(N_B * N_H * NQT), dim3(NT), 0, stream,
                           Q, K, V, caus, Y, W);
    }
}

// Round 5
// 333.614 us; speedup vs baseline: 1.9028x; 1.0818x over previous
//
#include <hip/hip_runtime.h>
#include <math.h>
#include <stdint.h>

// Problem constants
#define N_B 4
#define N_H 16
#define L_Q 2048
#define L_K 2048
#define E_D 1024
#define DH  64
#define QB  128          // q-rows per block (8 waves x 16 rows)
#define KB  64
#define NT  512
#define NQT (L_Q / QB)   // 16
#define NKT (L_K / KB)   // 32
#define LDP  72          // padded stride (f16) for Ps
#define LDPV 68

typedef _Float16 f16x2 __attribute__((ext_vector_type(2)));
typedef _Float16 f16x4 __attribute__((ext_vector_type(4)));
typedef _Float16 f16x8 __attribute__((ext_vector_type(8)));
typedef float    f32x4 __attribute__((ext_vector_type(4)));

__device__ __forceinline__ f16x4 pk4(float a, float b, float c, float d) {
    f16x2 lo = __builtin_bit_cast(f16x2, __builtin_amdgcn_cvt_pkrtz(a, b));
    f16x2 hi = __builtin_bit_cast(f16x2, __builtin_amdgcn_cvt_pkrtz(c, d));
    f16x4 r; r[0] = lo[0]; r[1] = lo[1]; r[2] = hi[0]; r[3] = hi[1];
    return r;
}

__device__ __forceinline__ void gload16(const _Float16* g, _Float16* l) {
    __builtin_amdgcn_global_load_lds(
        (const __attribute__((address_space(1))) void*)g,
        (__attribute__((address_space(3))) void*)l, 16, 0, 0);
}

// ======================= prep kernels =======================
__global__ __launch_bounds__(256)
void cvt_qk(const float* __restrict__ Q, const float* __restrict__ K,
            _Float16* __restrict__ Qh, _Float16* __restrict__ Kh)
{
    size_t i = ((size_t)blockIdx.x * 256 + threadIdx.x) * 8;
    float4 a = *(const float4*)(Q + i);
    float4 b = *(const float4*)(Q + i + 4);
    *(f16x4*)(Qh + i)     = pk4(a.x, a.y, a.z, a.w);
    *(f16x4*)(Qh + i + 4) = pk4(b.x, b.y, b.z, b.w);
    float4 c = *(const float4*)(K + i);
    float4 d = *(const float4*)(K + i + 4);
    *(f16x4*)(Kh + i)     = pk4(c.x, c.y, c.z, c.w);
    *(f16x4*)(Kh + i + 4) = pk4(d.x, d.y, d.z, d.w);
}

__global__ __launch_bounds__(256)
void cvt_vt(const float* __restrict__ V, _Float16* __restrict__ Vt)
{
    __shared__ _Float16 T[64][72];
    const int bid = blockIdx.x;
    const int st  = bid & 31;        // s-tile
    const int nh  = bid >> 5;
    const int n   = nh >> 4;
    const int h   = nh & 15;
    const int t   = threadIdx.x;
    const float* Vb = V + ((size_t)(n * L_K + st * 64)) * E_D + h * DH;
    #pragma unroll
    for (int i = 0; i < 4; ++i) {
        int lin = t + i * 256;
        int s = lin >> 4, d = (lin & 15) * 4;
        float4 v = *(const float4*)(Vb + (size_t)s * E_D + d);
        T[d + 0][s] = (_Float16)v.x; T[d + 1][s] = (_Float16)v.y;
        T[d + 2][s] = (_Float16)v.z; T[d + 3][s] = (_Float16)v.w;
    }
    __syncthreads();
    _Float16* Ob = Vt + ((size_t)nh * DH) * L_K + st * 64;
    #pragma unroll
    for (int j = 0; j < 2; ++j) {
        int lin = t + j * 256;
        int d = lin >> 3, sc = (lin & 7) * 8;
        *(f16x8*)(Ob + (size_t)d * L_K + sc) = *(const f16x8*)&T[d][sc];
    }
}

// ======================= main kernel =======================
__global__ __launch_bounds__(NT)
void mha_main(const _Float16* __restrict__ Qh, const _Float16* __restrict__ Kh,
              const _Float16* __restrict__ Vth, const int* __restrict__ causp,
              float* __restrict__ Yg, float* __restrict__ Wg)
{
    // linear swizzled tiles for global_load_lds; double-buffered
    __shared__ __attribute__((aligned(16))) _Float16 KsL[2][KB * DH];  // 8 KB each
    __shared__ __attribute__((aligned(16))) _Float16 VsL[2][DH * KB];  // 8 KB each
    __shared__ __attribute__((aligned(16))) _Float16 Ps[QB][LDP];
    __shared__ float linv[QB];

    const int tid  = threadIdx.x;
    const int lane = tid & 63;
    const int wid  = tid >> 6;            // 0..7, band of 16 q-rows
    const int bid0 = blockIdx.x;
    // bijective XCD swizzle: 1024 % 8 == 0
    const int bid  = ((bid0 & 7) << 7) + (bid0 >> 3);
    const int qt   = bid & (NQT - 1);
    const int nh   = bid >> 4;
    const int q0   = qt * QB;
    const int n    = nh >> 4;
    const int h    = nh & 15;
    const bool causal = (*causp) != 0;
    const float scale = 0.125f;

    const int lrow = lane & 15;           // q within 16 (C/D col, B-frag col)
    const int g    = lane >> 4;
    const int rb   = wid * 16;            // wave's q-band within block
    const int rsub = g * 4;
    const int kt_end = causal ? (2 * qt + 2) : NKT;

    float*  Ybase = Yg + ((size_t)(n * L_Q + q0)) * E_D + h * DH;
    float*  Wbase = Wg + ((size_t)nh * L_Q + q0) * L_K;

    // ---- staging source addresses (inverse-swizzled per-lane; rule #21) ----
    const int srow = wid * 8 + (lane >> 3);               // tile row (64 rows, 8 waves)
    const int scol = (((lane & 7) ^ ((lane >> 3) & 7)) << 3);
    const _Float16* Ksrc0 = Kh  + ((size_t)(n * L_K) + srow) * E_D + h * DH + scol;
    const _Float16* Vsrc0 = Vth + ((size_t)nh * DH + srow) * L_K + scol;

    // ---- swizzled fragment read offsets ----
    const int swz = (lrow & 7) << 4;                      // bytes
    const int cb0 = ((g * 16) ^ swz) >> 1;                // elements
    const int cb1 = ((64 + g * 16) ^ swz) >> 1;

    // ---- Q fragments straight from global f16 ----
    const _Float16* Qrow = Qh + ((size_t)(n * L_Q + q0 + rb + lrow)) * E_D + h * DH;
    const f16x8 qf0 = *(const f16x8*)(Qrow + g * 8);
    const f16x8 qf1 = *(const f16x8*)(Qrow + 32 + g * 8);

    #define STAGE_K(b, kt) gload16(Ksrc0 + (size_t)(kt) * KB * E_D, &KsL[b][wid * 512])
    #define STAGE_V(b, kt) gload16(Vsrc0 + (size_t)(kt) * KB,       &VsL[b][wid * 512])
    #define FRAG(buf, tc, half) (*(const f16x8*)&(buf)[(size_t)((tc) * 16 + lrow) * 64 + ((half) ? cb1 : cb0)])

    // ================= PASS A: row sums (m == 0) =================
    float l_part = 0.0f;
    STAGE_K(0, 0);
    __syncthreads();
    for (int kt = 0; kt < kt_end; ++kt) {
        const int cur = kt & 1;
        if (kt + 1 < kt_end) STAGE_K(cur ^ 1, kt + 1);

        f32x4 acc[4] = {};
        #pragma unroll
        for (int tc = 0; tc < 4; ++tc) {
            acc[tc] = __builtin_amdgcn_mfma_f32_16x16x32_f16(FRAG(KsL[cur], tc, 0), qf0, acc[tc], 0, 0, 0);
            acc[tc] = __builtin_amdgcn_mfma_f32_16x16x32_f16(FRAG(KsL[cur], tc, 1), qf1, acc[tc], 0, 0, 0);
        }
        const bool dm = causal && (kt >= 2 * qt);
        const int krel = (kt - 2 * qt) * 64;     // k col relative to block's q0
        #pragma unroll
        for (int tc = 0; tc < 4; ++tc) {
            #pragma unroll
            for (int i = 0; i < 4; ++i) {
                float v = acc[tc][i] * scale;    // S[q=rb+lrow][k=kt*64+tc*16+rsub+i]
                bool ok = !dm || (krel + tc * 16 + rsub + i <= rb + lrow);
                l_part += ok ? __expf(v) : 0.0f;
            }
        }
        __syncthreads();   // barrier drains vmcnt: prefetched buf ready
    }
    l_part += __shfl_xor(l_part, 16);
    l_part += __shfl_xor(l_part, 32);
    const float inv_l = 1.0f / l_part;
    linv[rb + lrow] = inv_l;   // 4 lanes write same value: benign

    // ================= PASS B: W write + O^T = V^T P^T =================
    f32x4 o[4] = {};
    STAGE_K(0, 0);
    STAGE_V(0, 0);
    __syncthreads();
    for (int kt = 0; kt < kt_end; ++kt) {
        const int cur = kt & 1;
        if (kt + 1 < kt_end) { STAGE_K(cur ^ 1, kt + 1); STAGE_V(cur ^ 1, kt + 1); }

        f32x4 acc[4] = {};
        #pragma unroll
        for (int tc = 0; tc < 4; ++tc) {
            acc[tc] = __builtin_amdgcn_mfma_f32_16x16x32_f16(FRAG(KsL[cur], tc, 0), qf0, acc[tc], 0, 0, 0);
            acc[tc] = __builtin_amdgcn_mfma_f32_16x16x32_f16(FRAG(KsL[cur], tc, 1), qf1, acc[tc], 0, 0, 0);
        }

        const bool dm = causal && (kt >= 2 * qt);
        const int krel = (kt - 2 * qt) * 64;
        #pragma unroll
        for (int tc = 0; tc < 4; ++tc) {
            float v, p0, p1, p2, p3;
            v = acc[tc][0] * scale;
            p0 = (!dm || (krel + tc * 16 + rsub + 0 <= rb + lrow)) ? __expf(v) : 0.0f;
            v = acc[tc][1] * scale;
            p1 = (!dm || (krel + tc * 16 + rsub + 1 <= rb + lrow)) ? __expf(v) : 0.0f;
            v = acc[tc][2] * scale;
            p2 = (!dm || (krel + tc * 16 + rsub + 2 <= rb + lrow)) ? __expf(v) : 0.0f;
            v = acc[tc][3] * scale;
            p3 = (!dm || (krel + tc * 16 + rsub + 3 <= rb + lrow)) ? __expf(v) : 0.0f;
            *(f16x4*)&Ps[rb + lrow][tc * 16 + rsub] = pk4(p0, p1, p2, p3);  // unnorm f16
        }
        // Ps rows rb..rb+15 written & read by this wave only: lgkmcnt orders it.

        f16x8 pf0 = *(const f16x8*)&Ps[rb + lrow][0 + g * 8];
        f16x8 pf1 = *(const f16x8*)&Ps[rb + lrow][32 + g * 8];
        #pragma unroll
        for (int tc = 0; tc < 4; ++tc) {
            o[tc] = __builtin_amdgcn_mfma_f32_16x16x32_f16(FRAG(VsL[cur], tc, 0), pf0, o[tc], 0, 0, 0);
            o[tc] = __builtin_amdgcn_mfma_f32_16x16x32_f16(FRAG(VsL[cur], tc, 1), pf1, o[tc], 0, 0, 0);
        }

        // ---- coalesced W store: lanes 0-15 cover one full row (256 B) ----
        {
            float* Wt = Wbase + (size_t)kt * KB;
            const int c0 = (lane & 15) * 4;
            #pragma unroll
            for (int j = 0; j < 4; ++j) {
                const int rl = rb + (lane >> 4) + 4 * j;   // this wave's rows
                f16x4 pv = *(const f16x4*)&Ps[rl][c0];
                const float s = linv[rl];
                float4 wv = make_float4((float)pv[0] * s, (float)pv[1] * s,
                                        (float)pv[2] * s, (float)pv[3] * s);
                *(float4*)(Wt + (size_t)rl * L_K + c0) = wv;
            }
        }
        __syncthreads();
    }

    // ---- Y write ----
    #pragma unroll
    for (int tc = 0; tc < 4; ++tc) {
        float4 yv = make_float4(o[tc][0] * inv_l, o[tc][1] * inv_l,
                                o[tc][2] * inv_l, o[tc][3] * inv_l);
        *(float4*)(Ybase + (size_t)(rb + lrow) * E_D + tc * 16 + rsub) = yv;
    }

    // ---- zero-fill masked upper columns ----
    if (causal && kt_end < NKT) {
        const int c0 = kt_end * KB;
        const int rem4 = (L_K - c0) >> 2;
        const float4 z = make_float4(0.f, 0.f, 0.f, 0.f);
        for (int r = 0; r < QB; ++r) {
            float* row = Wbase + (size_t)r * L_K + c0;
            for (int c4 = tid; c4 < rem4; c4 += NT) {
                *(float4*)(row + c4 * 4) = z;
            }
        }
    }
    #undef STAGE_K
    #undef STAGE_V
    #undef FRAG
}

// ======================= fallback (round-3 proven kernel) =======================
__global__ __launch_bounds__(256)
void mha_fwd_fallback(const float* __restrict__ Qg, const float* __restrict__ Kg,
                      const float* __restrict__ Vg, const int* __restrict__ causp,
                      float* __restrict__ Yg, float* __restrict__ Wg)
{
    __shared__ __attribute__((aligned(16))) _Float16 Qs[64][LDP];
    __shared__ __attribute__((aligned(16))) _Float16 Ks[64][LDP];
    __shared__ __attribute__((aligned(16))) _Float16 Psf[64][LDP];
    __shared__ __attribute__((aligned(16))) _Float16 Vt[DH][LDPV];

    const int tid  = threadIdx.x;
    const int lane = tid & 63;
    const int wid  = tid >> 6;
    const int bid  = blockIdx.x;
    const int qt   = bid & 31;
    const int nh   = bid >> 5;
    const int q0   = qt * 64;
    const int n    = nh >> 4;
    const int h    = nh & 15;
    const bool causal = (*causp) != 0;
    const float scale = 0.125f;

    const float* Qbase = Qg + ((size_t)(n * L_Q + q0)) * E_D + h * DH;
    const float* Kbase = Kg + ((size_t)n * L_K) * E_D + h * DH;
    const float* Vbase = Vg + ((size_t)n * L_K) * E_D + h * DH;
    float*       Ybase = Yg + ((size_t)(n * L_Q + q0)) * E_D + h * DH;
    float*       Wbase = Wg + ((size_t)nh * L_Q + q0) * L_K;

    const int lrow = lane & 15;
    const int lk   = (lane >> 4) * 8;
    const int rb   = wid * 16;
    const int rsub = (lane >> 4) * 4;
    const int kt_end = causal ? (qt + 1) : NKT;

    #pragma unroll
    for (int i = 0; i < 4; ++i) {
        int lin = tid + i * 256;
        int r = lin >> 4;
        int c = (lin & 15) * 4;
        float4 qv = *(const float4*)(Qbase + (size_t)r * E_D + c);
        *(f16x4*)&Qs[r][c] = pk4(qv.x, qv.y, qv.z, qv.w);
    }
    __syncthreads();
    const f16x8 qf0 = *(const f16x8*)&Qs[rb + lrow][lk];
    const f16x8 qf1 = *(const f16x8*)&Qs[rb + lrow][32 + lk];

    float l_part = 0.0f;
    for (int kt = 0; kt < kt_end; ++kt) {
        const float* Kt = Kbase + (size_t)kt * KB * E_D;
        __syncthreads();
        #pragma unroll
        for (int i = 0; i < 4; ++i) {
            int lin = tid + i * 256;
            int r = lin >> 4;
            int c = (lin & 15) * 4;
            float4 kv = *(const float4*)(Kt + (size_t)r * E_D + c);
            *(f16x4*)&Ks[r][c] = pk4(kv.x, kv.y, kv.z, kv.w);
        }
        __syncthreads();
        f32x4 acc[4] = {};
        #pragma unroll
        for (int tc = 0; tc < 4; ++tc) {
            f16x8 a0 = *(const f16x8*)&Ks[tc * 16 + lrow][lk];
            f16x8 a1 = *(const f16x8*)&Ks[tc * 16 + lrow][32 + lk];
            acc[tc] = __builtin_amdgcn_mfma_f32_16x16x32_f16(a0, qf0, acc[tc], 0, 0, 0);
            acc[tc] = __builtin_amdgcn_mfma_f32_16x16x32_f16(a1, qf1, acc[tc], 0, 0, 0);
        }
        const bool dm = causal && (kt == qt);
        #pragma unroll
        for (int tc = 0; tc < 4; ++tc) {
            #pragma unroll
            for (int i = 0; i < 4; ++i) {
                float v = acc[tc][i] * scale;
                bool ok = !dm || (tc * 16 + rsub + i <= rb + lrow);
                l_part += ok ? __expf(v) : 0.0f;
            }
        }
    }
    l_part += __shfl_xor(l_part, 16);
    l_part += __shfl_xor(l_part, 32);
    const float inv_l = 1.0f / l_part;

    f32x4 o[4] = {};
    for (int kt = 0; kt < kt_end; ++kt) {
        const float* Kt  = Kbase + (size_t)kt * KB * E_D;
        const float* Vtg = Vbase + (size_t)kt * KB * E_D;
        __syncthreads();
        #pragma unroll
        for (int i = 0; i < 4; ++i) {
            int lin = tid + i * 256;
            int r = lin >> 4;
            int c = (lin & 15) * 4;
            float4 kv = *(const float4*)(Kt + (size_t)r * E_D + c);
            *(f16x4*)&Ks[r][c] = pk4(kv.x, kv.y, kv.z, kv.w);
            int d   = lin & 63;
            int kk0 = (lin >> 6) * 4;
            float v0 = Vtg[(size_t)(kk0 + 0) * E_D + d];
            float v1 = Vtg[(size_t)(kk0 + 1) * E_D + d];
            float v2 = Vtg[(size_t)(kk0 + 2) * E_D + d];
            float v3 = Vtg[(size_t)(kk0 + 3) * E_D + d];
            *(f16x4*)&Vt[d][kk0] = pk4(v0, v1, v2, v3);
        }
        __syncthreads();
        f32x4 acc[4] = {};
        #pragma unroll
        for (int tc = 0; tc < 4; ++tc) {
            f16x8 a0 = *(const f16x8*)&Ks[tc * 16 + lrow][lk];
            f16x8 a1 = *(const f16x8*)&Ks[tc * 16 + lrow][32 + lk];
            acc[tc] = __builtin_amdgcn_mfma_f32_16x16x32_f16(a0, qf0, acc[tc], 0, 0, 0);
            acc[tc] = __builtin_amdgcn_mfma_f32_16x16x32_f16(a1, qf1, acc[tc], 0, 0, 0);
        }
        const bool dm = causal && (kt == qt);
        float* Wrow = Wbase + (size_t)(rb + lrow) * L_K + kt * KB;
        #pragma unroll
        for (int tc = 0; tc < 4; ++tc) {
            float v, p0, p1, p2, p3;
            v = acc[tc][0] * scale;
            p0 = (!dm || (tc * 16 + rsub + 0 <= rb + lrow)) ? __expf(v) : 0.0f;
            v = acc[tc][1] * scale;
            p1 = (!dm || (tc * 16 + rsub + 1 <= rb + lrow)) ? __expf(v) : 0.0f;
            v = acc[tc][2] * scale;
            p2 = (!dm || (tc * 16 + rsub + 2 <= rb + lrow)) ? __expf(v) : 0.0f;
            v = acc[tc][3] * scale;
            p3 = (!dm || (tc * 16 + rsub + 3 <= rb + lrow)) ? __expf(v) : 0.0f;
            float4 wv = make_float4(p0 * inv_l, p1 * inv_l, p2 * inv_l, p3 * inv_l);
            *(float4*)(Wrow + tc * 16 + rsub) = wv;
            *(f16x4*)&Psf[rb + lrow][tc * 16 + rsub] = pk4(p0, p1, p2, p3);
        }
        f16x8 pf0 = *(const f16x8*)&Psf[rb + lrow][lk];
        f16x8 pf1 = *(const f16x8*)&Psf[rb + lrow][32 + lk];
        #pragma unroll
        for (int tc = 0; tc < 4; ++tc) {
            f16x4 t0 = *(const f16x4*)&Vt[tc * 16 + lrow][lk];
            f16x4 t1 = *(const f16x4*)&Vt[tc * 16 + lrow][lk + 4];
            f16x8 a0 = __builtin_shufflevector(t0, t1, 0, 1, 2, 3, 4, 5, 6, 7);
            f16x4 t2 = *(const f16x4*)&Vt[tc * 16 + lrow][32 + lk];
            f16x4 t3 = *(const f16x4*)&Vt[tc * 16 + lrow][32 + lk + 4];
            f16x8 a1 = __builtin_shufflevector(t2, t3, 0, 1, 2, 3, 4, 5, 6, 7);
            o[tc] = __builtin_amdgcn_mfma_f32_16x16x32_f16(a0, pf0, o[tc], 0, 0, 0);
            o[tc] = __builtin_amdgcn_mfma_f32_16x16x32_f16(a1, pf1, o[tc], 0, 0, 0);
        }
    }
    #pragma unroll
    for (int tc = 0; tc < 4; ++tc) {
        float4 yv = make_float4(o[tc][0] * inv_l, o[tc][1] * inv_l,
                                o[tc][2] * inv_l, o[tc][3] * inv_l);
        *(float4*)(Ybase + (size_t)(rb + lrow) * E_D + tc * 16 + rsub) = yv;
    }
    if (causal && kt_end < NKT) {
        const int c0 = kt_end * KB;
        const int rem4 = (L_K - c0) >> 2;
        const float4 z = make_float4(0.f, 0.f, 0.f, 0.f);
        for (int r = 0; r < 64; ++r) {
            float* row = Wbase + (size_t)r * L_K + c0;
            for (int c4 = tid; c4 < rem4; c4 += 256) {
                *(float4*)(row + c4 * 4) = z;
            }
        }
    }
}

extern "C" void kernel_launch(void* const* d_in, const int* in_sizes, int n_in,
                              void* d_out, int out_size, void* d_ws, size_t ws_size,
                              hipStream_t stream) {
    const float* Q  = (const float*)d_in[0];
    const float* K  = (const float*)d_in[1];
    const float* V  = (const float*)d_in[2];
    const int* caus = (const int*)d_in[3];
    float* Y = (float*)d_out;
    float* W = (float*)d_out + (size_t)N_B * L_Q * E_D;

    const size_t elems = (size_t)N_B * L_Q * E_D;        // 8.4M
    const size_t need  = 3 * elems * sizeof(_Float16);   // ~48 MB

    if (ws_size >= need) {
        _Float16* Qh = (_Float16*)d_ws;
        _Float16* Kh = Qh + elems;
        _Float16* Vt = Kh + elems;
        hipLaunchKernelGGL(cvt_qk, dim3(elems / (256 * 8)), dim3(256), 0, stream, Q, K, Qh, Kh);
        hipLaunchKernelGGL(cvt_vt, dim3(N_B * N_H * (L_K / 64)), dim3(256), 0, stream, V, Vt);
        hipLaunchKernelGGL(mha_main, dim3(N_B * N_H * NQT), dim3(NT), 0, stream,
                           Qh, Kh, Vt, caus, Y, W);
    } else {
        hipLaunchKernelGGL(mha_fwd_fallback, dim3(N_B * N_H * 32), dim3(256), 0, stream,
                           Q, K, V, caus, Y, W);
    }
}